// Round 6
// baseline (104.885 us; speedup 1.0000x reference)
//
#include <hip/hip_runtime.h>
#include <math.h>

#define B_ 8
#define BIGF 3.4e38f

// ws layout (16-B aligned base):
//   packT  : B_*N float4 {-2x,-2y,-2z,|t|^2}
//   packS  : B_*M float4 { x,  y,  z, |s|^2}
//   rowmin : B_*N uint   (per-target min d^2, uint-ordered floats)
//   colmin : B_*M uint   (per-source min d^2)
//   partials_c[128], partials_a[128] floats

__global__ __launch_bounds__(256) void pack_kernel(
    const float* __restrict__ tar, const float* __restrict__ src,
    float4* __restrict__ packT, float4* __restrict__ packS,
    unsigned int* __restrict__ minarr, int N, int M)
{
    const int i = blockIdx.x * 256 + threadIdx.x;
    const int nT = B_ * N, nS = B_ * M;
    if (i < nT) {
        float x = tar[3 * i], y = tar[3 * i + 1], z = tar[3 * i + 2];
        packT[i] = make_float4(-2.f * x, -2.f * y, -2.f * z,
                               fmaf(x, x, fmaf(y, y, z * z)));
    } else if (i < nT + nS) {
        int j = i - nT;
        float x = src[3 * j], y = src[3 * j + 1], z = src[3 * j + 2];
        packS[j] = make_float4(x, y, z, fmaf(x, x, fmaf(y, y, z * z)));
    }
    if (i < nT + nS) minarr[i] = 0x7F800000u;  // +inf (rowmin then colmin)
}

// One pass over all (n,m) pairs feeding BOTH direction mins.
// grid = (N/64 strips, CSPLIT col-splits, B_). 256 thr, lane = tyl*16+tx.
// Lane holds 16 tar rows (a[16], strip rows tyl*16+r) in regs and 4 src cols
// per 64-col chunk (p[cr*16+tx]); waves stride disjoint chunks.
// d^2 = fma3(a.xyz, P.xyz, P.w) + a.w ; 2x2 sub-tiles -> 5 VALU/pair.
// Col-mins: 2 shuffles (tyl fold) + distributed atomicMin (64 contenders).
// Row-mins: tx fold + LDS wave fold + distributed atomicMin (CSPLIT cont.).
__global__ __launch_bounds__(256, 3) void fused_kernel(
    const float4* __restrict__ packT, const float4* __restrict__ packS,
    unsigned int* __restrict__ rowmin, unsigned int* __restrict__ colmin,
    int N, int M)
{
    const int b = blockIdx.z;
    const int strip = blockIdx.x;
    const int colbase = blockIdx.y * (M / gridDim.y);
    const int ncols = M / gridDim.y;           // cols this block covers
    const int t = threadIdx.x;
    const int wave = t >> 6, lane = t & 63;
    const int tx = lane & 15, tyl = lane >> 4;

    const float4* __restrict__ pT = packT + (size_t)b * N + strip * 64;
    const float4* __restrict__ pS = packS + (size_t)b * M + colbase;
    unsigned int* __restrict__ cm_out = colmin + (size_t)b * M + colbase;

    float4 a[16];
#pragma unroll
    for (int r = 0; r < 16; ++r) a[r] = pT[tyl * 16 + r];
    float rmin[16];
#pragma unroll
    for (int r = 0; r < 16; ++r) rmin[r] = BIGF;

    const int nch = ncols >> 6;                // 64-col chunks in this split
    int ch = wave;
    float4 p[4], pn[4];
    if (ch < nch) {
#pragma unroll
        for (int cr = 0; cr < 4; ++cr) p[cr] = pS[ch * 64 + cr * 16 + tx];
    }
    for (; ch < nch; ch += 4) {
        const int chn = ch + 4;
        if (chn < nch) {
#pragma unroll
            for (int cr = 0; cr < 4; ++cr) pn[cr] = pS[chn * 64 + cr * 16 + tx];
        }
#pragma unroll
        for (int cp = 0; cp < 4; cp += 2) {
            const float4 P0 = p[cp], P1 = p[cp + 1];
            float c0 = BIGF, c1 = BIGF;
#pragma unroll
            for (int r = 0; r < 16; r += 2) {
                float d00 = fmaf(a[r].x, P0.x, fmaf(a[r].y, P0.y,
                            fmaf(a[r].z, P0.z, P0.w))) + a[r].w;
                float d01 = fmaf(a[r].x, P1.x, fmaf(a[r].y, P1.y,
                            fmaf(a[r].z, P1.z, P1.w))) + a[r].w;
                float d10 = fmaf(a[r+1].x, P0.x, fmaf(a[r+1].y, P0.y,
                            fmaf(a[r+1].z, P0.z, P0.w))) + a[r+1].w;
                float d11 = fmaf(a[r+1].x, P1.x, fmaf(a[r+1].y, P1.y,
                            fmaf(a[r+1].z, P1.z, P1.w))) + a[r+1].w;
                rmin[r]   = fminf(rmin[r],   fminf(d00, d01));   // v_min3
                rmin[r+1] = fminf(rmin[r+1], fminf(d10, d11));
                c0 = fminf(c0, fminf(d00, d10));
                c1 = fminf(c1, fminf(d01, d11));
            }
            c0 = fminf(c0, __shfl_xor(c0, 16));
            c0 = fminf(c0, __shfl_xor(c0, 32));
            c1 = fminf(c1, __shfl_xor(c1, 16));
            c1 = fminf(c1, __shfl_xor(c1, 32));
            if (tyl == 0) {
                atomicMin(&cm_out[ch * 64 + cp * 16 + tx],
                          __float_as_uint(fmaxf(c0, 0.f)));
                atomicMin(&cm_out[ch * 64 + (cp + 1) * 16 + tx],
                          __float_as_uint(fmaxf(c1, 0.f)));
            }
        }
#pragma unroll
        for (int cr = 0; cr < 4; ++cr) p[cr] = pn[cr];
    }

    // Row-mins: fold across tx (16 lanes share each row), LDS across waves,
    // then one 64-lane distributed atomicMin (CSPLIT contenders per addr).
#pragma unroll
    for (int r = 0; r < 16; ++r) {
        float v = rmin[r];
        v = fminf(v, __shfl_xor(v, 1));
        v = fminf(v, __shfl_xor(v, 2));
        v = fminf(v, __shfl_xor(v, 4));
        v = fminf(v, __shfl_xor(v, 8));
        rmin[r] = v;
    }
    __shared__ float wr[4][64];
    if (tx == 0) {
#pragma unroll
        for (int r = 0; r < 16; ++r) wr[wave][tyl * 16 + r] = rmin[r];
    }
    __syncthreads();
    if (wave == 0) {
        float v = fminf(fminf(wr[0][lane], wr[1][lane]),
                        fminf(wr[2][lane], wr[3][lane]));
        atomicMin(&rowmin[(size_t)b * N + strip * 64 + lane],
                  __float_as_uint(fmaxf(v, 0.f)));
    }
}

// 128-block stripe reduce: sqrt both min arrays, one partial per block per
// direction (plain stores, always written).
__global__ __launch_bounds__(256) void reduce1_kernel(
    const unsigned int* __restrict__ rowmin,
    const unsigned int* __restrict__ colmin,
    float* __restrict__ partials, int N, int M)
{
    const int nt = B_ * N, ns = B_ * M;
    const int gid = blockIdx.x * 256 + threadIdx.x;
    const int stride = gridDim.x * 256;
    float s_t = 0.f, s_s = 0.f;
    for (int i = gid; i < nt; i += stride) s_t += sqrtf(__uint_as_float(rowmin[i]));
    for (int i = gid; i < ns; i += stride) s_s += sqrtf(__uint_as_float(colmin[i]));
#pragma unroll
    for (int off = 32; off > 0; off >>= 1) {
        s_t += __shfl_down(s_t, off);
        s_s += __shfl_down(s_s, off);
    }
    __shared__ float rt[4], rs[4];
    const int wid = threadIdx.x >> 6, lid = threadIdx.x & 63;
    if (lid == 0) { rt[wid] = s_t; rs[wid] = s_s; }
    __syncthreads();
    if (threadIdx.x == 0) {
        partials[blockIdx.x]       = rt[0] + rt[1] + rt[2] + rt[3];
        partials[128 + blockIdx.x] = rs[0] + rs[1] + rs[2] + rs[3];
    }
}

__global__ __launch_bounds__(128) void finalize_kernel(
    const float* __restrict__ partials, float* __restrict__ outp, int N, int M)
{
    const int t = threadIdx.x;
    float s_t = partials[t];
    float s_s = partials[128 + t];
#pragma unroll
    for (int off = 32; off > 0; off >>= 1) {
        s_t += __shfl_down(s_t, off);
        s_s += __shfl_down(s_s, off);
    }
    __shared__ float rt[2], rs[2];
    if ((t & 63) == 0) { rt[t >> 6] = s_t; rs[t >> 6] = s_s; }
    __syncthreads();
    if (t == 0) {
        float complete = (rt[0] + rt[1]) / (float)(B_ * N);
        float accuracy = (rs[0] + rs[1]) / (float)(B_ * M);
        outp[0] = accuracy;
        outp[1] = complete;
        outp[2] = 0.5f * (accuracy + complete);
    }
}

extern "C" void kernel_launch(void* const* d_in, const int* in_sizes, int n_in,
                              void* d_out, int out_size, void* d_ws, size_t ws_size,
                              hipStream_t stream) {
    const float* tar = (const float*)d_in[0];
    const float* src = (const float*)d_in[1];
    const int N = in_sizes[0] / (B_ * 3);
    const int M = in_sizes[1] / (B_ * 3);

    float4* packT = (float4*)d_ws;
    float4* packS = packT + (size_t)B_ * N;
    unsigned int* rowmin = (unsigned int*)(packS + (size_t)B_ * M);
    unsigned int* colmin = rowmin + (size_t)B_ * N;
    float* partials = (float*)(colmin + (size_t)B_ * M);

    pack_kernel<<<dim3((B_ * (N + M) + 255) / 256), dim3(256), 0, stream>>>(
        tar, src, packT, packS, rowmin, N, M);

    const int nstrips = N / 64;
    const int csplit  = 4;                      // M/4 = 1024 cols per block
    fused_kernel<<<dim3(nstrips, csplit, B_), dim3(256), 0, stream>>>(
        packT, packS, rowmin, colmin, N, M);

    reduce1_kernel<<<dim3(128), dim3(256), 0, stream>>>(
        rowmin, colmin, partials, N, M);

    finalize_kernel<<<dim3(1), dim3(128), 0, stream>>>(
        partials, (float*)d_out, N, M);
}

// Round 7
// 91.903 us; speedup vs baseline: 1.1413x; 1.1413x over previous
//
#include <hip/hip_runtime.h>
#include <math.h>

#define B_ 8
#define BIGF 3.4e38f

// ws layout (16-B aligned base):
//   packT  : B_*N float4 {-2x,-2y,-2z,|t|^2}
//   packS  : B_*M float4 { x,  y,  z, |s|^2}
//   rowmin : B_*N uint   (per-target min d^2, uint-ordered floats)
//   colmin : B_*M uint   (per-source min d^2)
//   partials[256] floats

__global__ __launch_bounds__(256) void pack_kernel(
    const float* __restrict__ tar, const float* __restrict__ src,
    float4* __restrict__ packT, float4* __restrict__ packS,
    unsigned int* __restrict__ minarr, int N, int M)
{
    const int i = blockIdx.x * 256 + threadIdx.x;
    const int nT = B_ * N, nS = B_ * M;
    if (i < nT) {
        float x = tar[3 * i], y = tar[3 * i + 1], z = tar[3 * i + 2];
        packT[i] = make_float4(-2.f * x, -2.f * y, -2.f * z,
                               fmaf(x, x, fmaf(y, y, z * z)));
    } else if (i < nT + nS) {
        int j = i - nT;
        float x = src[3 * j], y = src[3 * j + 1], z = src[3 * j + 2];
        packS[j] = make_float4(x, y, z, fmaf(x, x, fmaf(y, y, z * z)));
    }
    if (i < nT + nS) minarr[i] = 0x7F800000u;  // +inf (rowmin then colmin)
}

// One pass over all (n,m) pairs feeding BOTH direction mins.
// grid = (N/32 strips, CSPLIT col-splits, B_). 256 thr, lane = tyl*16+tx.
// Lane holds 8 tar rows (a[8], strip rows tyl*8+r) in regs and 4 src cols
// per 64-col chunk (p[cr*16+tx]); waves stride disjoint chunks.
// Per-lane hot state ~95 VGPR -> no spill, ~5 waves/SIMD. NO min-waves bound
// (R6's (256,3) capped VGPR=84 and spilled 27 MB to scratch).
// d^2 = fma3(a.xyz, P.xyz, P.w) + a.w ; 2x2 sub-tiles -> 5 VALU/pair.
__global__ __launch_bounds__(256) void fused_kernel(
    const float4* __restrict__ packT, const float4* __restrict__ packS,
    unsigned int* __restrict__ rowmin, unsigned int* __restrict__ colmin,
    int N, int M, int csplit)
{
    const int b = blockIdx.z;
    const int strip = blockIdx.x;              // 32-row strip
    const int ncols = M / csplit;
    const int colbase = blockIdx.y * ncols;
    const int t = threadIdx.x;
    const int wave = t >> 6, lane = t & 63;
    const int tx = lane & 15, tyl = lane >> 4;

    const float4* __restrict__ pT = packT + (size_t)b * N + strip * 32;
    const float4* __restrict__ pS = packS + (size_t)b * M + colbase;
    unsigned int* __restrict__ cm_out = colmin + (size_t)b * M + colbase;

    float4 a[8];
#pragma unroll
    for (int r = 0; r < 8; ++r) a[r] = pT[tyl * 8 + r];
    float rmin[8];
#pragma unroll
    for (int r = 0; r < 8; ++r) rmin[r] = BIGF;

    const int nch = ncols >> 6;                // 64-col chunks in this split
    int ch = wave;
    float4 p[4], pn[4];
    if (ch < nch) {
#pragma unroll
        for (int cr = 0; cr < 4; ++cr) p[cr] = pS[ch * 64 + cr * 16 + tx];
    }
    for (; ch < nch; ch += 4) {
        const int chn = ch + 4;
        if (chn < nch) {
#pragma unroll
            for (int cr = 0; cr < 4; ++cr) pn[cr] = pS[chn * 64 + cr * 16 + tx];
        }
#pragma unroll
        for (int cp = 0; cp < 4; cp += 2) {
            const float4 P0 = p[cp], P1 = p[cp + 1];
            float c0 = BIGF, c1 = BIGF;
#pragma unroll
            for (int r = 0; r < 8; r += 2) {
                float d00 = fmaf(a[r].x, P0.x, fmaf(a[r].y, P0.y,
                            fmaf(a[r].z, P0.z, P0.w))) + a[r].w;
                float d01 = fmaf(a[r].x, P1.x, fmaf(a[r].y, P1.y,
                            fmaf(a[r].z, P1.z, P1.w))) + a[r].w;
                float d10 = fmaf(a[r+1].x, P0.x, fmaf(a[r+1].y, P0.y,
                            fmaf(a[r+1].z, P0.z, P0.w))) + a[r+1].w;
                float d11 = fmaf(a[r+1].x, P1.x, fmaf(a[r+1].y, P1.y,
                            fmaf(a[r+1].z, P1.z, P1.w))) + a[r+1].w;
                rmin[r]   = fminf(rmin[r],   fminf(d00, d01));   // v_min3
                rmin[r+1] = fminf(rmin[r+1], fminf(d10, d11));
                c0 = fminf(c0, fminf(d00, d10));
                c1 = fminf(c1, fminf(d01, d11));
            }
            c0 = fminf(c0, __shfl_xor(c0, 16));
            c0 = fminf(c0, __shfl_xor(c0, 32));
            c1 = fminf(c1, __shfl_xor(c1, 16));
            c1 = fminf(c1, __shfl_xor(c1, 32));
            if (tyl == 0) {
                atomicMin(&cm_out[ch * 64 + cp * 16 + tx],
                          __float_as_uint(fmaxf(c0, 0.f)));
                atomicMin(&cm_out[ch * 64 + (cp + 1) * 16 + tx],
                          __float_as_uint(fmaxf(c1, 0.f)));
            }
        }
#pragma unroll
        for (int cr = 0; cr < 4; ++cr) p[cr] = pn[cr];
    }

    // Row-mins: fold across tx (16 lanes share each row), LDS across waves,
    // then one distributed atomicMin (csplit contenders per address).
#pragma unroll
    for (int r = 0; r < 8; ++r) {
        float v = rmin[r];
        v = fminf(v, __shfl_xor(v, 1));
        v = fminf(v, __shfl_xor(v, 2));
        v = fminf(v, __shfl_xor(v, 4));
        v = fminf(v, __shfl_xor(v, 8));
        rmin[r] = v;
    }
    __shared__ float wr[4][32];
    if (tx == 0) {
#pragma unroll
        for (int r = 0; r < 8; ++r) wr[wave][tyl * 8 + r] = rmin[r];
    }
    __syncthreads();
    if (wave == 0 && lane < 32) {
        float v = fminf(fminf(wr[0][lane], wr[1][lane]),
                        fminf(wr[2][lane], wr[3][lane]));
        atomicMin(&rowmin[(size_t)b * N + strip * 32 + lane],
                  __float_as_uint(fmaxf(v, 0.f)));
    }
}

// 128-block stripe reduce: sqrt both min arrays, one partial per block per
// direction (plain stores, always written).
__global__ __launch_bounds__(256) void reduce1_kernel(
    const unsigned int* __restrict__ rowmin,
    const unsigned int* __restrict__ colmin,
    float* __restrict__ partials, int N, int M)
{
    const int nt = B_ * N, ns = B_ * M;
    const int gid = blockIdx.x * 256 + threadIdx.x;
    const int stride = gridDim.x * 256;
    float s_t = 0.f, s_s = 0.f;
    for (int i = gid; i < nt; i += stride) s_t += sqrtf(__uint_as_float(rowmin[i]));
    for (int i = gid; i < ns; i += stride) s_s += sqrtf(__uint_as_float(colmin[i]));
#pragma unroll
    for (int off = 32; off > 0; off >>= 1) {
        s_t += __shfl_down(s_t, off);
        s_s += __shfl_down(s_s, off);
    }
    __shared__ float rt[4], rs[4];
    const int wid = threadIdx.x >> 6, lid = threadIdx.x & 63;
    if (lid == 0) { rt[wid] = s_t; rs[wid] = s_s; }
    __syncthreads();
    if (threadIdx.x == 0) {
        partials[blockIdx.x]       = rt[0] + rt[1] + rt[2] + rt[3];
        partials[128 + blockIdx.x] = rs[0] + rs[1] + rs[2] + rs[3];
    }
}

__global__ __launch_bounds__(128) void finalize_kernel(
    const float* __restrict__ partials, float* __restrict__ outp, int N, int M)
{
    const int t = threadIdx.x;
    float s_t = partials[t];
    float s_s = partials[128 + t];
#pragma unroll
    for (int off = 32; off > 0; off >>= 1) {
        s_t += __shfl_down(s_t, off);
        s_s += __shfl_down(s_s, off);
    }
    __shared__ float rt[2], rs[2];
    if ((t & 63) == 0) { rt[t >> 6] = s_t; rs[t >> 6] = s_s; }
    __syncthreads();
    if (t == 0) {
        float complete = (rt[0] + rt[1]) / (float)(B_ * N);
        float accuracy = (rs[0] + rs[1]) / (float)(B_ * M);
        outp[0] = accuracy;
        outp[1] = complete;
        outp[2] = 0.5f * (accuracy + complete);
    }
}

extern "C" void kernel_launch(void* const* d_in, const int* in_sizes, int n_in,
                              void* d_out, int out_size, void* d_ws, size_t ws_size,
                              hipStream_t stream) {
    const float* tar = (const float*)d_in[0];
    const float* src = (const float*)d_in[1];
    const int N = in_sizes[0] / (B_ * 3);
    const int M = in_sizes[1] / (B_ * 3);

    float4* packT = (float4*)d_ws;
    float4* packS = packT + (size_t)B_ * N;
    unsigned int* rowmin = (unsigned int*)(packS + (size_t)B_ * M);
    unsigned int* colmin = rowmin + (size_t)B_ * N;
    float* partials = (float*)(colmin + (size_t)B_ * M);

    pack_kernel<<<dim3((B_ * (N + M) + 255) / 256), dim3(256), 0, stream>>>(
        tar, src, packT, packS, rowmin, N, M);

    const int nstrips = N / 32;                 // 128 strips of 32 rows
    const int csplit  = 2;                      // M/2 = 2048 cols per block
    fused_kernel<<<dim3(nstrips, csplit, B_), dim3(256), 0, stream>>>(
        packT, packS, rowmin, colmin, N, M, csplit);

    reduce1_kernel<<<dim3(128), dim3(256), 0, stream>>>(
        rowmin, colmin, partials, N, M);

    finalize_kernel<<<dim3(1), dim3(128), 0, stream>>>(
        partials, (float*)d_out, N, M);
}

// Round 8
// 83.548 us; speedup vs baseline: 1.2554x; 1.1000x over previous
//
#include <hip/hip_runtime.h>
#include <math.h>

#define B_ 8
#define BIGF 3.4e38f

// ws layout (16-B aligned base):
//   packT  : B_*N float4 {x,y,z,|t|^2}
//   packS  : B_*M float4 {x,y,z,|s|^2}
//   minarr : B_*N uint rowmin (per-target min d^2, uint-ordered floats)
//            followed by B_*M uint colmin (per-source min d^2)

// Pack points to float4 (plain form; -2 scaling applied at query load),
// init the min arrays to +inf, zero d_out. One node, ~1.5 us.
__global__ __launch_bounds__(256) void pack_kernel(
    const float* __restrict__ tar, const float* __restrict__ src,
    float4* __restrict__ packT, float4* __restrict__ packS,
    unsigned int* __restrict__ minarr, float* __restrict__ outp,
    int N, int M)
{
    const int i = blockIdx.x * 256 + threadIdx.x;
    const int nT = B_ * N, nS = B_ * M;
    if (i < nT) {
        float x = tar[3 * i], y = tar[3 * i + 1], z = tar[3 * i + 2];
        packT[i] = make_float4(x, y, z, fmaf(x, x, fmaf(y, y, z * z)));
    } else if (i < nT + nS) {
        int j = i - nT;
        float x = src[3 * j], y = src[3 * j + 1], z = src[3 * j + 2];
        packS[j] = make_float4(x, y, z, fmaf(x, x, fmaf(y, y, z * z)));
    }
    if (i < nT + nS) minarr[i] = 0x7F800000u;  // +inf
    if (i < 3) outp[i] = 0.f;                  // accuracy, complete, chamfer
}

// R3-proven two-pass structure (both dirs via z), packed-float4 I/O.
// blockIdx.z in [0, 2*B_): z<B_ query=tar ref=src; else query=src ref=tar.
// d^2 = |q|^2 + (|p|^2 - 2 q.p): inner = 3 fma/pair + min3/2pairs; |q|^2
// added after the min (monotone). Cross-block combine: distributed uint
// atomicMin (d^2 clamped >= 0 so uint order == float order).
template <int QPT, int CHUNK>
__global__ __launch_bounds__(256) void minsq_kernel(
    const float4* __restrict__ packT, const float4* __restrict__ packS,
    unsigned int* __restrict__ minarr, int N, int M)
{
    const int z   = blockIdx.z;
    const int dir = (z >= B_) ? 1 : 0;
    const int b   = dir ? (z - B_) : z;
    const float4* __restrict__ qry = dir ? packS : packT;
    const float4* __restrict__ pts = dir ? packT : packS;
    const int K = dir ? M : N;   // query count
    const int L = dir ? N : M;   // reference count
    unsigned int* __restrict__ out =
        minarr + (dir ? (size_t)B_ * N : (size_t)0) + (size_t)b * K;

    const int base = blockIdx.y * CHUNK;
    if (base >= L) return;
    const int cnt = min(CHUNK, L - base);

    __shared__ float4 sp[CHUNK];
    const float4* __restrict__ psrc = pts + (size_t)b * L + base;
    const int t = threadIdx.x;
    for (int i = t; i < cnt; i += 256) sp[i] = psrc[i];
    __syncthreads();

    const int qbase = blockIdx.x * (256 * QPT);
    float qx2[QPT], qy2[QPT], qz2[QPT], qw[QPT], mn[QPT];
#pragma unroll
    for (int k = 0; k < QPT; ++k) {
        int qi = qbase + k * 256 + t;
        if (qi < K) {
            float4 q = qry[(size_t)b * K + qi];
            qx2[k] = -2.f * q.x; qy2[k] = -2.f * q.y; qz2[k] = -2.f * q.z;
            qw[k] = q.w;
        } else {
            qx2[k] = 0.f; qy2[k] = 0.f; qz2[k] = 0.f; qw[k] = 0.f;
        }
        mn[k] = BIGF;
    }

    if (cnt == CHUNK) {
#pragma unroll 4
        for (int j = 0; j < CHUNK; j += 2) {
            float4 p0 = sp[j];
            float4 p1 = sp[j + 1];
#pragma unroll
            for (int k = 0; k < QPT; ++k) {
                float d0 = fmaf(qx2[k], p0.x, fmaf(qy2[k], p0.y,
                           fmaf(qz2[k], p0.z, p0.w)));
                float d1 = fmaf(qx2[k], p1.x, fmaf(qy2[k], p1.y,
                           fmaf(qz2[k], p1.z, p1.w)));
                mn[k] = fminf(mn[k], fminf(d0, d1));   // v_min3_f32
            }
        }
    } else {
        int j = 0;
        for (; j + 1 < cnt; j += 2) {
            float4 p0 = sp[j];
            float4 p1 = sp[j + 1];
#pragma unroll
            for (int k = 0; k < QPT; ++k) {
                float d0 = fmaf(qx2[k], p0.x, fmaf(qy2[k], p0.y,
                           fmaf(qz2[k], p0.z, p0.w)));
                float d1 = fmaf(qx2[k], p1.x, fmaf(qy2[k], p1.y,
                           fmaf(qz2[k], p1.z, p1.w)));
                mn[k] = fminf(mn[k], fminf(d0, d1));
            }
        }
        if (j < cnt) {
            float4 p0 = sp[j];
#pragma unroll
            for (int k = 0; k < QPT; ++k) {
                float d0 = fmaf(qx2[k], p0.x, fmaf(qy2[k], p0.y,
                           fmaf(qz2[k], p0.z, p0.w)));
                mn[k] = fminf(mn[k], d0);
            }
        }
    }

#pragma unroll
    for (int k = 0; k < QPT; ++k) {
        int qi = qbase + k * 256 + t;
        if (qi < K) {
            float d2 = fmaxf(mn[k] + qw[k], 0.f);  // clamp roundoff negatives
            atomicMin(&out[qi], __float_as_uint(d2));
        }
    }
}

// Merged reduce+finalize: 32 blocks stripe-sum sqrt of both regions, then 3
// scaled atomicAdds into d_out (zeroed by pack_kernel). 96 same-line atomics
// ~1.4 us — cheaper than a second reduce node (~2.6 us gap).
__global__ __launch_bounds__(256) void reduce_kernel(
    const unsigned int* __restrict__ minarr, float* __restrict__ outp,
    int N, int M)
{
    const int nt = B_ * N, ns = B_ * M;
    const int gid = blockIdx.x * 256 + threadIdx.x;
    const int stride = gridDim.x * 256;
    float s_t = 0.f, s_s = 0.f;
    for (int i = gid; i < nt; i += stride)
        s_t += sqrtf(__uint_as_float(minarr[i]));
    for (int i = gid; i < ns; i += stride)
        s_s += sqrtf(__uint_as_float(minarr[nt + i]));
#pragma unroll
    for (int off = 32; off > 0; off >>= 1) {
        s_t += __shfl_down(s_t, off);
        s_s += __shfl_down(s_s, off);
    }
    __shared__ float rt[4], rs[4];
    const int wid = threadIdx.x >> 6, lid = threadIdx.x & 63;
    if (lid == 0) { rt[wid] = s_t; rs[wid] = s_s; }
    __syncthreads();
    if (threadIdx.x == 0) {
        float ct = (rt[0] + rt[1] + rt[2] + rt[3]) / (float)nt;  // complete
        float ac = (rs[0] + rs[1] + rs[2] + rs[3]) / (float)ns;  // accuracy
        atomicAdd(&outp[0], ac);
        atomicAdd(&outp[1], ct);
        atomicAdd(&outp[2], 0.5f * (ac + ct));
    }
}

extern "C" void kernel_launch(void* const* d_in, const int* in_sizes, int n_in,
                              void* d_out, int out_size, void* d_ws, size_t ws_size,
                              hipStream_t stream) {
    const float* tar = (const float*)d_in[0];
    const float* src = (const float*)d_in[1];
    const int N = in_sizes[0] / (B_ * 3);
    const int M = in_sizes[1] / (B_ * 3);

    float4* packT = (float4*)d_ws;
    float4* packS = packT + (size_t)B_ * N;
    unsigned int* minarr = (unsigned int*)(packS + (size_t)B_ * M);
    float* outp = (float*)d_out;

    pack_kernel<<<dim3((B_ * (N + M) + 255) / 256), dim3(256), 0, stream>>>(
        tar, src, packT, packS, minarr, outp, N, M);

    constexpr int QPT = 8, CHUNK = 128;
    const int KL = (N > M) ? N : M;
    const int gx = (KL + 256 * QPT - 1) / (256 * QPT);   // 2
    const int gy = (KL + CHUNK - 1) / CHUNK;             // 32
    dim3 grid(gx, gy, 2 * B_);                            // 1024 blocks
    minsq_kernel<QPT, CHUNK><<<grid, dim3(256), 0, stream>>>(
        packT, packS, minarr, N, M);

    reduce_kernel<<<dim3(32), dim3(256), 0, stream>>>(minarr, outp, N, M);
}